// Round 6
// baseline (298.431 us; speedup 1.0000x reference)
//
#include <hip/hip_runtime.h>
#include <hip/hip_cooperative_groups.h>
#include <math.h>

namespace cg = cooperative_groups;

namespace {
constexpr int kTokens = 8192;
constexpr int kHS = 4096;
constexpr float kTol = 1e-4f;
constexpr float kEps = 1e-8f;
constexpr int kMaxIters = 1000;
constexpr int kSinkBlocks = 64;  // regular launch; 64 << 256 CUs -> co-resident
// ws layout: [tags: 2*64 uint][gdata: 2*64*64 f32][part: S*8192*64 f32]
constexpr size_t kTagFloats = 128;
constexpr size_t kGdataFloats = 2 * 64 * 64;
constexpr size_t kPartOff = kTagFloats + kGdataFloats;
constexpr size_t kSliceFloats = (size_t)kTokens * 64;
constexpr size_t kWtpFloats = (size_t)(kHS / 4) * 64 * 4;  // fallback only
}  // namespace

__device__ __forceinline__ float wave_sum(float v) {
#pragma unroll
  for (int o = 32; o; o >>= 1) v += __shfl_xor(v, o, 64);
  return v;
}

// ---------- K1: split-K logits. grid = 64*S blocks, 128 threads ----------
// Tile 128 tokens x 64 experts x KS. Thread tile 8x8 (tx=expert/8, ty=token/8).
// X: per-thread direct global float4 reads of its own 8 consecutive rows
//    (8x dup across tx served by XCD L2; no LDS for X at all).
// W: LDS transposed [k][expert], stride 68; lane<->row mapping makes every
//    staging write and compute read <=2-way (free) bank access.
__global__ void __launch_bounds__(128, 2)
k_logits(const float* __restrict__ X, const float* __restrict__ W,
         float* __restrict__ part, int KS) {
  __shared__ float wsh[32][68];
  const int tid = threadIdx.x;
  const int tx = tid & 7;          // expert group 8*tx..8*tx+7
  const int ty = tid >> 3;         // token group 8*ty..8*ty+7 (0..15)
  const int tb = blockIdx.x & 63;  // token block
  const int s = blockIdx.x >> 6;   // k-slice
  const int t0 = tb * 128;
  const int k0 = s * KS;

  // W stager: thread covers row wr (0..63), k-chunks wc0..wc0+3
  const int wr = tid & 63;
  const int wc0 = (tid >> 6) * 4;  // wave 0: chunks 0..3, wave 1: 4..7

  const float* xbase = X + (size_t)(t0 + 8 * ty) * kHS + k0;
  const float* wbase = W + (size_t)wr * kHS + k0;

  float acc[8][8];
#pragma unroll
  for (int i = 0; i < 8; ++i)
#pragma unroll
    for (int j = 0; j < 8; ++j) acc[i][j] = 0.0f;

  const int nkt = KS / 32;
  float4 wpre[4];
#pragma unroll
  for (int p = 0; p < 4; ++p)
    wpre[p] = *(const float4*)(wbase + 4 * (wc0 + p));

  for (int kt = 0; kt < nkt; ++kt) {
    __syncthreads();  // prior tile's reads done
#pragma unroll
    for (int p = 0; p < 4; ++p) {
      const int c = wc0 + p;
      // write banks: (4c+i)*68 + wr -> const + wr mod 32 -> 2-way, free
      wsh[4 * c + 0][wr] = wpre[p].x;
      wsh[4 * c + 1][wr] = wpre[p].y;
      wsh[4 * c + 2][wr] = wpre[p].z;
      wsh[4 * c + 3][wr] = wpre[p].w;
    }
    __syncthreads();
    if (kt + 1 < nkt) {
      const int ko = 32 * (kt + 1);
#pragma unroll
      for (int p = 0; p < 4; ++p)
        wpre[p] = *(const float4*)(wbase + ko + 4 * (wc0 + p));
    }
    const int kk0 = kt * 32;
#pragma unroll 2
    for (int kb = 0; kb < 8; ++kb) {
      float4 xq[8];
#pragma unroll
      for (int i = 0; i < 8; ++i)
        xq[i] = *(const float4*)(xbase + (size_t)i * kHS + kk0 + 4 * kb);
#pragma unroll
      for (int u = 0; u < 4; ++u) {
        // read banks: 68k + 8tx -> {0,8,16,24}x2 -> 2-way, free
        const float4 w0 = *(const float4*)&wsh[4 * kb + u][8 * tx];
        const float4 w1 = *(const float4*)&wsh[4 * kb + u][8 * tx + 4];
        const float wr8[8] = {w0.x, w0.y, w0.z, w0.w, w1.x, w1.y, w1.z, w1.w};
#pragma unroll
        for (int i = 0; i < 8; ++i) {
          const float xv = (u == 0)   ? xq[i].x
                           : (u == 1) ? xq[i].y
                           : (u == 2) ? xq[i].z
                                      : xq[i].w;
#pragma unroll
          for (int j = 0; j < 8; ++j)
            acc[i][j] = fmaf(xv, wr8[j], acc[i][j]);
        }
      }
    }
  }

  float* pb = part + ((size_t)s * kTokens + t0 + 8 * ty) * 64 + 8 * tx;
#pragma unroll
  for (int i = 0; i < 8; ++i) {
    *(float4*)(pb + (size_t)i * 64) =
        make_float4(acc[i][0], acc[i][1], acc[i][2], acc[i][3]);
    *(float4*)(pb + (size_t)i * 64 + 4) =
        make_float4(acc[i][4], acc[i][5], acc[i][6], acc[i][7]);
  }
}

// ---------- K2: sinkhorn + top-2 + softmax, custom tag barrier ----------
__global__ void __launch_bounds__(1024, 1)
k_sinkhorn(const float* __restrict__ part, int S, float* __restrict__ out,
           unsigned* __restrict__ tags, float* __restrict__ gdata) {
  const int tid = threadIdx.x;
  const int lane = tid & 63;
  const int wid = __builtin_amdgcn_readfirstlane(tid >> 6);  // 0..15
  const int blk = blockIdx.x;                                // 0..63
  __shared__ float lds[1024];

  const int t0 = blk * 128 + wid * 8;
  float lg[8], cst[8];
#pragma unroll
  for (int t = 0; t < 8; ++t) {
    float a = 0.0f;
    for (int s = 0; s < S; ++s)
      a += part[((size_t)s * kTokens + t0 + t) * 64 + lane];
    lg[t] = a;
    cst[t] = expf(a);
  }

  float d1 = 1.0f;
  float d0v[8];
  int buf = 0;
  for (int it = 0; it < kMaxIters; ++it) {
    float p = 0.0f;
#pragma unroll
    for (int t = 0; t < 8; ++t) {
      const float s = wave_sum(d1 * cst[t]);
      const float d0t = (1.0f / 8192.0f) / (s + kEps);
      d0v[t] = d0t;
      p = fmaf(d0t, cst[t], p);
    }
    __syncthreads();
    lds[wid * 64 + lane] = p;
    __syncthreads();
    const unsigned want = (unsigned)(it + 1);
    if (wid == 0) {
      float bp = 0.0f;
#pragma unroll
      for (int w = 0; w < 16; ++w) bp += lds[w * 64 + lane];
      __hip_atomic_store(&gdata[((size_t)buf * 64 + blk) * 64 + lane], bp,
                         __ATOMIC_RELAXED, __HIP_MEMORY_SCOPE_AGENT);
      __threadfence();
      if (lane == 0)
        __hip_atomic_store(&tags[buf * 64 + blk], want, __ATOMIC_RELEASE,
                           __HIP_MEMORY_SCOPE_AGENT);
      while (__hip_atomic_load(&tags[buf * 64 + lane], __ATOMIC_ACQUIRE,
                               __HIP_MEMORY_SCOPE_AGENT) != want) {
        __builtin_amdgcn_s_sleep(1);
      }
    }
    __syncthreads();
    float s2 = 0.0f;
#pragma unroll
    for (int i = 0; i < 4; ++i)
      s2 += __hip_atomic_load(
          &gdata[((size_t)buf * 64 + wid * 4 + i) * 64 + lane],
          __ATOMIC_RELAXED, __HIP_MEMORY_SCOPE_AGENT);
    lds[wid * 64 + lane] = s2;
    __syncthreads();
    float colsum = 0.0f;
#pragma unroll
    for (int w = 0; w < 16; ++w) colsum += lds[w * 64 + lane];
    const float d1n = (1.0f / 64.0f) / (colsum + kEps);
    const float err = wave_sum(fabsf(d1 - d1n)) * (1.0f / 64.0f);
    d1 = d1n;
    buf ^= 1;
    if (err <= kTol) break;
  }

#pragma unroll
  for (int t = 0; t < 8; ++t) {
    const float lgv = lg[t];
    float m = lgv;
#pragma unroll
    for (int o = 32; o; o >>= 1) m = fmaxf(m, __shfl_xor(m, o, 64));
    const float ex = expf(lgv - m);
    const float den = wave_sum(ex);
    const float prob = ex / den;

    const float v = (d1 * cst[t]) * d0v[t];
    float v1 = v;
    int i1 = lane;
#pragma unroll
    for (int o = 32; o; o >>= 1) {
      const float ov = __shfl_xor(v1, o, 64);
      const int oi = __shfl_xor(i1, o, 64);
      if (ov > v1 || (ov == v1 && oi < i1)) { v1 = ov; i1 = oi; }
    }
    float v2 = (lane == i1) ? -INFINITY : v;
    int i2 = lane;
#pragma unroll
    for (int o = 32; o; o >>= 1) {
      const float ov = __shfl_xor(v2, o, 64);
      const int oi = __shfl_xor(i2, o, 64);
      if (ov > v2 || (ov == v2 && oi < i2)) { v2 = ov; i2 = oi; }
    }
    const float p1 = __shfl(prob, i1, 64);
    const float p2 = __shfl(prob, i2, 64);
    if (lane == 0) {
      const int row = t0 + t;
      out[row * 2 + 0] = p1;
      out[row * 2 + 1] = p2;
      out[2 * kTokens + row * 2 + 0] = (float)i1;
      out[2 * kTokens + row * 2 + 1] = (float)i2;
    }
  }
}

// ---------- fallback: round-1 monolithic cooperative kernel ----------
__global__ void __launch_bounds__(256, 1)
sinkhorn_router(const float* __restrict__ X, const float* __restrict__ W,
                float* __restrict__ out, float* __restrict__ ws) {
  cg::grid_group grid = cg::this_grid();
  const int tid = threadIdx.x;
  const int lane = tid & 63;
  const int wid = __builtin_amdgcn_readfirstlane(tid >> 6);
  const int blk = blockIdx.x;

  float4* wtp = reinterpret_cast<float4*>(ws);
  float* gpart = ws + kWtpFloats;
  __shared__ float lds[256];

  {
    const int j = blk * 256 + tid;
    const int e = j & 63;
    const int k4 = j >> 6;
    wtp[j] = *reinterpret_cast<const float4*>(W + (size_t)e * kHS + 4 * (size_t)k4);
  }
  grid.sync();

  const int t0 = blk * 32 + wid * 8;
  const float* xb = X + (size_t)t0 * kHS;
  float lg[8];
#pragma unroll
  for (int t = 0; t < 8; ++t) lg[t] = 0.0f;

#pragma unroll 2
  for (int k4 = 0; k4 < kHS / 4; ++k4) {
    const float4 w = wtp[k4 * 64 + lane];
#pragma unroll
    for (int t = 0; t < 8; ++t) {
      const float* xr = xb + (size_t)t * kHS + 4 * (size_t)k4;
      float a = lg[t];
      a = fmaf(xr[0], w.x, a);
      a = fmaf(xr[1], w.y, a);
      a = fmaf(xr[2], w.z, a);
      a = fmaf(xr[3], w.w, a);
      lg[t] = a;
    }
  }

  float cst[8];
#pragma unroll
  for (int t = 0; t < 8; ++t) cst[t] = expf(lg[t]);

  float d1 = 1.0f;
  float d0v[8];
  int buf = 0;
  for (int it = 0; it < kMaxIters; ++it) {
    float p = 0.0f;
#pragma unroll
    for (int t = 0; t < 8; ++t) {
      const float s = wave_sum(d1 * cst[t]);
      const float d0t = (1.0f / 8192.0f) / (s + kEps);
      d0v[t] = d0t;
      p = fmaf(d0t, cst[t], p);
    }
    __syncthreads();
    lds[wid * 64 + lane] = p;
    __syncthreads();
    if (wid == 0) {
      const float bp =
          lds[lane] + lds[64 + lane] + lds[128 + lane] + lds[192 + lane];
      gpart[buf * (256 * 64) + blk * 64 + lane] = bp;
    }
    grid.sync();
    const float* gp = gpart + buf * (256 * 64);
    float s = 0.0f;
#pragma unroll 8
    for (int b = 0; b < 64; ++b) s += gp[(wid * 64 + b) * 64 + lane];
    lds[wid * 64 + lane] = s;
    __syncthreads();
    const float colsum =
        lds[lane] + lds[64 + lane] + lds[128 + lane] + lds[192 + lane];
    const float d1n = (1.0f / 64.0f) / (colsum + kEps);
    const float err = wave_sum(fabsf(d1 - d1n)) * (1.0f / 64.0f);
    d1 = d1n;
    buf ^= 1;
    if (err <= kTol) break;
  }

#pragma unroll
  for (int t = 0; t < 8; ++t) {
    const float lgv = lg[t];
    float m = lgv;
#pragma unroll
    for (int o = 32; o; o >>= 1) m = fmaxf(m, __shfl_xor(m, o, 64));
    const float ex = expf(lgv - m);
    const float den = wave_sum(ex);
    const float prob = ex / den;

    const float v = (d1 * cst[t]) * d0v[t];
    float v1 = v;
    int i1 = lane;
#pragma unroll
    for (int o = 32; o; o >>= 1) {
      const float ov = __shfl_xor(v1, o, 64);
      const int oi = __shfl_xor(i1, o, 64);
      if (ov > v1 || (ov == v1 && oi < i1)) { v1 = ov; i1 = oi; }
    }
    float v2 = (lane == i1) ? -INFINITY : v;
    int i2 = lane;
#pragma unroll
    for (int o = 32; o; o >>= 1) {
      const float ov = __shfl_xor(v2, o, 64);
      const int oi = __shfl_xor(i2, o, 64);
      if (ov > v2 || (ov == v2 && oi < i2)) { v2 = ov; i2 = oi; }
    }
    const float p1 = __shfl(prob, i1, 64);
    const float p2 = __shfl(prob, i2, 64);
    if (lane == 0) {
      const int row = t0 + t;
      out[row * 2 + 0] = p1;
      out[row * 2 + 1] = p2;
      out[2 * kTokens + row * 2 + 0] = (float)i1;
      out[2 * kTokens + row * 2 + 1] = (float)i2;
    }
  }
}

extern "C" void kernel_launch(void* const* d_in, const int* in_sizes, int n_in,
                              void* d_out, int out_size, void* d_ws,
                              size_t ws_size, hipStream_t stream) {
  const float* X = (const float*)d_in[0];
  const float* W = (const float*)d_in[1];
  float* out = (float*)d_out;
  float* ws = (float*)d_ws;

  int S = 0;
  for (int cand : {16, 8, 4, 2, 1}) {
    const size_t need = (kPartOff + (size_t)cand * kSliceFloats) * 4;
    if (need <= ws_size) { S = cand; break; }
  }

  if (S == 0) {
    void* args[] = {(void*)&X, (void*)&W, (void*)&out, (void*)&ws};
    hipLaunchCooperativeKernel((const void*)sinkhorn_router, dim3(256),
                               dim3(256), args, 0, stream);
    return;
  }

  unsigned* tags = reinterpret_cast<unsigned*>(ws);
  float* gdata = ws + kTagFloats;
  float* part = ws + kPartOff;

  const int KS = kHS / S;
  hipLaunchKernelGGL(k_logits, dim3(64 * S), dim3(128), 0, stream, X, W, part,
                     KS);
  hipLaunchKernelGGL(k_sinkhorn, dim3(kSinkBlocks), dim3(1024), 0, stream,
                     part, S, out, tags, gdata);
}

// Round 7
// 281.836 us; speedup vs baseline: 1.0589x; 1.0589x over previous
//
#include <hip/hip_runtime.h>
#include <hip/hip_cooperative_groups.h>
#include <math.h>

namespace cg = cooperative_groups;

namespace {
constexpr int kTokens = 8192;
constexpr int kHS = 4096;
constexpr float kTol = 1e-4f;
constexpr float kEps = 1e-8f;
constexpr int kMaxIters = 1000;
constexpr int kSinkBlocks = 64;  // regular launch; 64 << 256 CUs -> co-resident
// ws layout: [tags: 2*64 uint][gdata: 2*64*64 f32][part: S*8192*64 f32]
constexpr size_t kTagFloats = 128;
constexpr size_t kGdataFloats = 2 * 64 * 64;
constexpr size_t kPartOff = kTagFloats + kGdataFloats;
constexpr size_t kSliceFloats = (size_t)kTokens * 64;
constexpr size_t kWtpFloats = (size_t)(kHS / 4) * 64 * 4;  // fallback only
}  // namespace

__device__ __forceinline__ float wave_sum(float v) {
#pragma unroll
  for (int o = 32; o; o >>= 1) v += __shfl_xor(v, o, 64);
  return v;
}

// ---------- K1: split-K SGEMM logits. grid = 64*S blocks, 128 threads ----------
// Block tile 128 tokens x 64 experts x KS, thread tile 8x8, BK=32.
// X in LDS transposed [k][col] with xor-swizzle col=(((row>>2)^(k>>2))<<2)|(row&3):
//   staging writes and compute reads are both <=2-way bank access (free).
// W in LDS [k][expert] stride 68, wave-uniform k-chunk staging (conflict-free).
// Global->reg prefetch one kt ahead hides HBM/L2 latency (round-6 lesson).
__global__ void __launch_bounds__(128, 2)
k_logits(const float* __restrict__ X, const float* __restrict__ W,
         float* __restrict__ part, int KS) {
  __shared__ float xs[32][132];
  __shared__ float wsh[32][68];
  const int tid = threadIdx.x;
  const int tx = tid & 7;          // expert group 8*tx..8*tx+7
  const int ty = tid >> 3;         // token group 8*ty..8*ty+7 (0..15)
  const int tb = blockIdx.x & 63;  // token block
  const int s = blockIdx.x >> 6;   // k-slice
  const int t0 = tb * 128;
  const int k0 = s * KS;

  const int cx = tid & 7;   // X stager: k-chunk (16B), k = 4cx..4cx+3
  const int rx = tid >> 3;  // X stager: row base (0..15), rows rx+16p
  const int wr = tid & 63;  // W stager: row (=expert)
  const int wc0 = (tid >> 6) * 4;  // W stager: wave-uniform k-chunk base

  const float* xsrc = X + (size_t)(t0 + rx) * kHS + k0 + 4 * cx;
  const float* wbase = W + (size_t)wr * kHS + k0;

  float acc[8][8];
#pragma unroll
  for (int i = 0; i < 8; ++i)
#pragma unroll
    for (int j = 0; j < 8; ++j) acc[i][j] = 0.0f;

  const int nkt = KS / 32;
  float4 xa[8], wpre[4];
#pragma unroll
  for (int p = 0; p < 8; ++p)
    xa[p] = *(const float4*)(xsrc + (size_t)p * 16 * kHS);
#pragma unroll
  for (int p = 0; p < 4; ++p)
    wpre[p] = *(const float4*)(wbase + 4 * (wc0 + p));

  for (int kt = 0; kt < nkt; ++kt) {
    __syncthreads();  // prior tile's reads complete
    // X staging: k = 4cx+i (k>>2 == cx), swizzled column
#pragma unroll
    for (int p = 0; p < 8; ++p) {
      const int row = rx + 16 * p;
      const int col = (((row >> 2) ^ cx) << 2) | (row & 3);
      xs[4 * cx + 0][col] = xa[p].x;
      xs[4 * cx + 1][col] = xa[p].y;
      xs[4 * cx + 2][col] = xa[p].z;
      xs[4 * cx + 3][col] = xa[p].w;
    }
    // W staging: wave-uniform chunk -> bank = lane + const (conflict-free)
#pragma unroll
    for (int p = 0; p < 4; ++p) {
      const int c = wc0 + p;
      wsh[4 * c + 0][wr] = wpre[p].x;
      wsh[4 * c + 1][wr] = wpre[p].y;
      wsh[4 * c + 2][wr] = wpre[p].z;
      wsh[4 * c + 3][wr] = wpre[p].w;
    }
    __syncthreads();
    if (kt + 1 < nkt) {  // prefetch next tile into registers
      const int ko = 32 * (kt + 1);
#pragma unroll
      for (int p = 0; p < 8; ++p)
        xa[p] = *(const float4*)(xsrc + (size_t)p * 16 * kHS + ko);
#pragma unroll
      for (int p = 0; p < 4; ++p)
        wpre[p] = *(const float4*)(wbase + ko + 4 * (wc0 + p));
    }
#pragma unroll 8
    for (int k = 0; k < 32; ++k) {
      const int sw = (k >> 2) & 7;
      const float4 x0 = *(const float4*)&xs[k][((2 * ty) ^ sw) << 2];
      const float4 x1 = *(const float4*)&xs[k][((2 * ty + 1) ^ sw) << 2];
      const float4 w0 = *(const float4*)&wsh[k][8 * tx];
      const float4 w1 = *(const float4*)&wsh[k][8 * tx + 4];
      const float xr8[8] = {x0.x, x0.y, x0.z, x0.w, x1.x, x1.y, x1.z, x1.w};
      const float wr8[8] = {w0.x, w0.y, w0.z, w0.w, w1.x, w1.y, w1.z, w1.w};
#pragma unroll
      for (int i = 0; i < 8; ++i)
#pragma unroll
        for (int j = 0; j < 8; ++j)
          acc[i][j] = fmaf(xr8[i], wr8[j], acc[i][j]);
    }
  }

  float* pb = part + ((size_t)s * kTokens + t0 + 8 * ty) * 64 + 8 * tx;
#pragma unroll
  for (int i = 0; i < 8; ++i) {
    *(float4*)(pb + (size_t)i * 64) =
        make_float4(acc[i][0], acc[i][1], acc[i][2], acc[i][3]);
    *(float4*)(pb + (size_t)i * 64 + 4) =
        make_float4(acc[i][4], acc[i][5], acc[i][6], acc[i][7]);
  }
}

// ---------- K2: sinkhorn + top-2 + softmax, custom tag barrier ----------
__global__ void __launch_bounds__(1024, 1)
k_sinkhorn(const float* __restrict__ part, int S, float* __restrict__ out,
           unsigned* __restrict__ tags, float* __restrict__ gdata) {
  const int tid = threadIdx.x;
  const int lane = tid & 63;
  const int wid = __builtin_amdgcn_readfirstlane(tid >> 6);  // 0..15
  const int blk = blockIdx.x;                                // 0..63
  __shared__ float lds[1024];

  const int t0 = blk * 128 + wid * 8;
  float lg[8], cst[8];
#pragma unroll
  for (int t = 0; t < 8; ++t) {
    float a = 0.0f;
    for (int s = 0; s < S; ++s)
      a += part[((size_t)s * kTokens + t0 + t) * 64 + lane];
    lg[t] = a;
    cst[t] = expf(a);
  }

  float d1 = 1.0f;
  float d0v[8];
  int buf = 0;
  for (int it = 0; it < kMaxIters; ++it) {
    float p = 0.0f;
#pragma unroll
    for (int t = 0; t < 8; ++t) {
      const float s = wave_sum(d1 * cst[t]);
      const float d0t = (1.0f / 8192.0f) / (s + kEps);
      d0v[t] = d0t;
      p = fmaf(d0t, cst[t], p);
    }
    __syncthreads();
    lds[wid * 64 + lane] = p;
    __syncthreads();
    const unsigned want = (unsigned)(it + 1);
    if (wid == 0) {
      float bp = 0.0f;
#pragma unroll
      for (int w = 0; w < 16; ++w) bp += lds[w * 64 + lane];
      __hip_atomic_store(&gdata[((size_t)buf * 64 + blk) * 64 + lane], bp,
                         __ATOMIC_RELAXED, __HIP_MEMORY_SCOPE_AGENT);
      __threadfence();
      if (lane == 0)
        __hip_atomic_store(&tags[buf * 64 + blk], want, __ATOMIC_RELEASE,
                           __HIP_MEMORY_SCOPE_AGENT);
      while (__hip_atomic_load(&tags[buf * 64 + lane], __ATOMIC_ACQUIRE,
                               __HIP_MEMORY_SCOPE_AGENT) != want) {
        __builtin_amdgcn_s_sleep(1);
      }
    }
    __syncthreads();
    float s2 = 0.0f;
#pragma unroll
    for (int i = 0; i < 4; ++i)
      s2 += __hip_atomic_load(
          &gdata[((size_t)buf * 64 + wid * 4 + i) * 64 + lane],
          __ATOMIC_RELAXED, __HIP_MEMORY_SCOPE_AGENT);
    lds[wid * 64 + lane] = s2;
    __syncthreads();
    float colsum = 0.0f;
#pragma unroll
    for (int w = 0; w < 16; ++w) colsum += lds[w * 64 + lane];
    const float d1n = (1.0f / 64.0f) / (colsum + kEps);
    const float err = wave_sum(fabsf(d1 - d1n)) * (1.0f / 64.0f);
    d1 = d1n;
    buf ^= 1;
    if (err <= kTol) break;
  }

#pragma unroll
  for (int t = 0; t < 8; ++t) {
    const float lgv = lg[t];
    float m = lgv;
#pragma unroll
    for (int o = 32; o; o >>= 1) m = fmaxf(m, __shfl_xor(m, o, 64));
    const float ex = expf(lgv - m);
    const float den = wave_sum(ex);
    const float prob = ex / den;

    const float v = (d1 * cst[t]) * d0v[t];
    float v1 = v;
    int i1 = lane;
#pragma unroll
    for (int o = 32; o; o >>= 1) {
      const float ov = __shfl_xor(v1, o, 64);
      const int oi = __shfl_xor(i1, o, 64);
      if (ov > v1 || (ov == v1 && oi < i1)) { v1 = ov; i1 = oi; }
    }
    float v2 = (lane == i1) ? -INFINITY : v;
    int i2 = lane;
#pragma unroll
    for (int o = 32; o; o >>= 1) {
      const float ov = __shfl_xor(v2, o, 64);
      const int oi = __shfl_xor(i2, o, 64);
      if (ov > v2 || (ov == v2 && oi < i2)) { v2 = ov; i2 = oi; }
    }
    const float p1 = __shfl(prob, i1, 64);
    const float p2 = __shfl(prob, i2, 64);
    if (lane == 0) {
      const int row = t0 + t;
      out[row * 2 + 0] = p1;
      out[row * 2 + 1] = p2;
      out[2 * kTokens + row * 2 + 0] = (float)i1;
      out[2 * kTokens + row * 2 + 1] = (float)i2;
    }
  }
}

// ---------- fallback: round-1 monolithic cooperative kernel ----------
__global__ void __launch_bounds__(256, 1)
sinkhorn_router(const float* __restrict__ X, const float* __restrict__ W,
                float* __restrict__ out, float* __restrict__ ws) {
  cg::grid_group grid = cg::this_grid();
  const int tid = threadIdx.x;
  const int lane = tid & 63;
  const int wid = __builtin_amdgcn_readfirstlane(tid >> 6);
  const int blk = blockIdx.x;

  float4* wtp = reinterpret_cast<float4*>(ws);
  float* gpart = ws + kWtpFloats;
  __shared__ float lds[256];

  {
    const int j = blk * 256 + tid;
    const int e = j & 63;
    const int k4 = j >> 6;
    wtp[j] = *reinterpret_cast<const float4*>(W + (size_t)e * kHS + 4 * (size_t)k4);
  }
  grid.sync();

  const int t0 = blk * 32 + wid * 8;
  const float* xb = X + (size_t)t0 * kHS;
  float lg[8];
#pragma unroll
  for (int t = 0; t < 8; ++t) lg[t] = 0.0f;

#pragma unroll 2
  for (int k4 = 0; k4 < kHS / 4; ++k4) {
    const float4 w = wtp[k4 * 64 + lane];
#pragma unroll
    for (int t = 0; t < 8; ++t) {
      const float* xr = xb + (size_t)t * kHS + 4 * (size_t)k4;
      float a = lg[t];
      a = fmaf(xr[0], w.x, a);
      a = fmaf(xr[1], w.y, a);
      a = fmaf(xr[2], w.z, a);
      a = fmaf(xr[3], w.w, a);
      lg[t] = a;
    }
  }

  float cst[8];
#pragma unroll
  for (int t = 0; t < 8; ++t) cst[t] = expf(lg[t]);

  float d1 = 1.0f;
  float d0v[8];
  int buf = 0;
  for (int it = 0; it < kMaxIters; ++it) {
    float p = 0.0f;
#pragma unroll
    for (int t = 0; t < 8; ++t) {
      const float s = wave_sum(d1 * cst[t]);
      const float d0t = (1.0f / 8192.0f) / (s + kEps);
      d0v[t] = d0t;
      p = fmaf(d0t, cst[t], p);
    }
    __syncthreads();
    lds[wid * 64 + lane] = p;
    __syncthreads();
    if (wid == 0) {
      const float bp =
          lds[lane] + lds[64 + lane] + lds[128 + lane] + lds[192 + lane];
      gpart[buf * (256 * 64) + blk * 64 + lane] = bp;
    }
    grid.sync();
    const float* gp = gpart + buf * (256 * 64);
    float s = 0.0f;
#pragma unroll 8
    for (int b = 0; b < 64; ++b) s += gp[(wid * 64 + b) * 64 + lane];
    lds[wid * 64 + lane] = s;
    __syncthreads();
    const float colsum =
        lds[lane] + lds[64 + lane] + lds[128 + lane] + lds[192 + lane];
    const float d1n = (1.0f / 64.0f) / (colsum + kEps);
    const float err = wave_sum(fabsf(d1 - d1n)) * (1.0f / 64.0f);
    d1 = d1n;
    buf ^= 1;
    if (err <= kTol) break;
  }

#pragma unroll
  for (int t = 0; t < 8; ++t) {
    const float lgv = lg[t];
    float m = lgv;
#pragma unroll
    for (int o = 32; o; o >>= 1) m = fmaxf(m, __shfl_xor(m, o, 64));
    const float ex = expf(lgv - m);
    const float den = wave_sum(ex);
    const float prob = ex / den;

    const float v = (d1 * cst[t]) * d0v[t];
    float v1 = v;
    int i1 = lane;
#pragma unroll
    for (int o = 32; o; o >>= 1) {
      const float ov = __shfl_xor(v1, o, 64);
      const int oi = __shfl_xor(i1, o, 64);
      if (ov > v1 || (ov == v1 && oi < i1)) { v1 = ov; i1 = oi; }
    }
    float v2 = (lane == i1) ? -INFINITY : v;
    int i2 = lane;
#pragma unroll
    for (int o = 32; o; o >>= 1) {
      const float ov = __shfl_xor(v2, o, 64);
      const int oi = __shfl_xor(i2, o, 64);
      if (ov > v2 || (ov == v2 && oi < i2)) { v2 = ov; i2 = oi; }
    }
    const float p1 = __shfl(prob, i1, 64);
    const float p2 = __shfl(prob, i2, 64);
    if (lane == 0) {
      const int row = t0 + t;
      out[row * 2 + 0] = p1;
      out[row * 2 + 1] = p2;
      out[2 * kTokens + row * 2 + 0] = (float)i1;
      out[2 * kTokens + row * 2 + 1] = (float)i2;
    }
  }
}

extern "C" void kernel_launch(void* const* d_in, const int* in_sizes, int n_in,
                              void* d_out, int out_size, void* d_ws,
                              size_t ws_size, hipStream_t stream) {
  const float* X = (const float*)d_in[0];
  const float* W = (const float*)d_in[1];
  float* out = (float*)d_out;
  float* ws = (float*)d_ws;

  int S = 0;
  for (int cand : {16, 8, 4, 2, 1}) {
    const size_t need = (kPartOff + (size_t)cand * kSliceFloats) * 4;
    if (need <= ws_size) { S = cand; break; }
  }

  if (S == 0) {
    void* args[] = {(void*)&X, (void*)&W, (void*)&out, (void*)&ws};
    hipLaunchCooperativeKernel((const void*)sinkhorn_router, dim3(256),
                               dim3(256), args, 0, stream);
    return;
  }

  unsigned* tags = reinterpret_cast<unsigned*>(ws);
  float* gdata = ws + kTagFloats;
  float* part = ws + kPartOff;

  const int KS = kHS / S;
  hipLaunchKernelGGL(k_logits, dim3(64 * S), dim3(128), 0, stream, X, W, part,
                     KS);
  hipLaunchKernelGGL(k_sinkhorn, dim3(kSinkBlocks), dim3(1024), 0, stream,
                     part, S, out, tags, gdata);
}